// Round 9
// baseline (336.235 us; speedup 1.0000x reference)
//
#include <hip/hip_runtime.h>
#include <hip/hip_bf16.h>

// Problem constants
#define B 4
#define S 2048
#define E 1024
#define H 16
#define D 64
#define M_ROWS (B * S)   // 8192
#define HD (H * D)       // 1024
#define QKVW (3 * HD)    // 3072

#define QBLK 128
#define KVBLK 64

typedef __attribute__((ext_vector_type(8))) short bf16x8;   // 8 bf16 = 4 VGPRs
typedef __attribute__((ext_vector_type(4))) float f32x4;

typedef const __attribute__((address_space(1))) void* gas_ptr;
typedef __attribute__((address_space(3))) void* las_ptr;
#define GLD16(g, l) __builtin_amdgcn_global_load_lds((gas_ptr)(g), (las_ptr)(l), 16, 0, 0)

// ---------------------------------------------------------------------------
// LayerNorm: one block (256 threads) per row of E=1024, bf16 output
// ---------------------------------------------------------------------------
__global__ void ln_kernel(const float* __restrict__ x,
                          const float* __restrict__ gamma,
                          const float* __restrict__ beta,
                          __hip_bfloat16* __restrict__ xn) {
    const int row = blockIdx.x;
    const float* xr = x + (size_t)row * E;
    __hip_bfloat16* yr = xn + (size_t)row * E;

    float vals[4];
    float sum = 0.f, sumsq = 0.f;
#pragma unroll
    for (int t = 0; t < 4; ++t) {
        float v = xr[threadIdx.x + t * 256];
        vals[t] = v;
        sum += v;
        sumsq += v * v;
    }
#pragma unroll
    for (int o = 32; o > 0; o >>= 1) {
        sum += __shfl_down(sum, o);
        sumsq += __shfl_down(sumsq, o);
    }
    __shared__ float s1[4], s2[4];
    const int wid = threadIdx.x >> 6, lane = threadIdx.x & 63;
    if (lane == 0) { s1[wid] = sum; s2[wid] = sumsq; }
    __syncthreads();
    if (threadIdx.x == 0) {
        float a = s1[0] + s1[1] + s1[2] + s1[3];
        float b2 = s2[0] + s2[1] + s2[2] + s2[3];
        float mu = a / (float)E;
        float var = b2 / (float)E - mu * mu;
        s1[0] = mu;
        s2[0] = rsqrtf(var + 1e-5f);
    }
    __syncthreads();
    const float mu = s1[0], rstd = s2[0];
#pragma unroll
    for (int t = 0; t < 4; ++t) {
        int c = threadIdx.x + t * 256;
        yr[c] = __float2bfloat16((vals[t] - mu) * rstd * gamma[c] + beta[c]);
    }
}

// ---------------------------------------------------------------------------
// Transpose fp32 W[K,N] -> bf16 Wt[N,K]  (LDS-tiled, coalesced both sides)
// ---------------------------------------------------------------------------
__global__ void transpose_to_bf16(const float* __restrict__ W,
                                  __hip_bfloat16* __restrict__ Wt,
                                  int K, int N) {
    __shared__ float t[64][65];
    const int n0 = blockIdx.x * 64, k0 = blockIdx.y * 64;
    const int tx = threadIdx.x & 63, ty = threadIdx.x >> 6;
#pragma unroll
    for (int i = ty; i < 64; i += 4)
        t[i][tx] = W[(size_t)(k0 + i) * N + n0 + tx];
    __syncthreads();
#pragma unroll
    for (int i = ty; i < 64; i += 4)
        Wt[(size_t)(n0 + i) * K + k0 + tx] = __float2bfloat16(t[tx][i]);
}

// pack bq|bk|bv into one 3072 vector
__global__ void pack_bias(const float* __restrict__ bq, const float* __restrict__ bk,
                          const float* __restrict__ bv, float* __restrict__ o) {
    const int t = threadIdx.x;
    o[t] = bq[t]; o[HD + t] = bk[t]; o[2 * HD + t] = bv[t];
}

// ---------------------------------------------------------------------------
// bf16 MFMA GEMM: C[M,N] = A[M,K] @ Bt[N,K]^T + bias  (+ residual, fp32 out)
// 128x128 tile, BK=64, 256 threads (4 waves); global_load_lds staging.
// ---------------------------------------------------------------------------
template<bool BF16OUT>
__global__ __launch_bounds__(256)
void gemm_mfma(const __hip_bfloat16* __restrict__ A,
               const __hip_bfloat16* __restrict__ Bt,
               const float* __restrict__ bias,
               const float* __restrict__ residual,
               void* __restrict__ Cout,
               int Mdim, int Ndim, int Kdim) {
    __shared__ __align__(16) short sA[128 * 64];   // 16 KB
    __shared__ __align__(16) short sB[128 * 64];   // 16 KB

    const int tid = threadIdx.x;
    const int lane = tid & 63;
    const int wv = tid >> 6;
    const int wr = wv >> 1, wc = wv & 1;
    const int fr = lane & 15;
    const int kg = (lane >> 4) * 8;
    const int brow = blockIdx.y * 128;
    const int bcol = blockIdx.x * 128;

    // staging: chunk c = tid + 256*i -> row c>>3 (= r0+32i), 16B slot c&7
    const int r0 = tid >> 3;          // 0..31
    const int slot = tid & 7;
    const __hip_bfloat16* gA = A + (size_t)(brow + r0) * Kdim + slot * 8;
    const __hip_bfloat16* gB = Bt + (size_t)(bcol + r0) * Kdim + slot * 8;

    f32x4 acc[4][4] = {};

    for (int k0 = 0; k0 < Kdim; k0 += 64) {
#pragma unroll
        for (int i = 0; i < 4; ++i) {
            GLD16(gA + (size_t)(32 * i) * Kdim + k0, sA + (size_t)(tid + 256 * i) * 8);
            GLD16(gB + (size_t)(32 * i) * Kdim + k0, sB + (size_t)(tid + 256 * i) * 8);
        }
        __syncthreads();
#pragma unroll
        for (int kk = 0; kk < 64; kk += 32) {
            bf16x8 af[4], bfr[4];
#pragma unroll
            for (int mi = 0; mi < 4; ++mi)
                af[mi] = *(const bf16x8*)&sA[(wr * 64 + mi * 16 + fr) * 64 + kk + kg];
#pragma unroll
            for (int ni = 0; ni < 4; ++ni)
                bfr[ni] = *(const bf16x8*)&sB[(wc * 64 + ni * 16 + fr) * 64 + kk + kg];
#pragma unroll
            for (int mi = 0; mi < 4; ++mi)
#pragma unroll
                for (int ni = 0; ni < 4; ++ni)
                    acc[mi][ni] = __builtin_amdgcn_mfma_f32_16x16x32_bf16(
                        af[mi], bfr[ni], acc[mi][ni], 0, 0, 0);
        }
        __syncthreads();
    }

#pragma unroll
    for (int mi = 0; mi < 4; ++mi) {
        const int rbase = brow + wr * 64 + mi * 16 + ((lane >> 4) << 2);
#pragma unroll
        for (int ni = 0; ni < 4; ++ni) {
            const int c = bcol + wc * 64 + ni * 16 + fr;
            const float bv = bias[c];
#pragma unroll
            for (int qd = 0; qd < 4; ++qd) {
                const size_t idx = (size_t)(rbase + qd) * Ndim + c;
                float v = acc[mi][ni][qd] + bv;
                if constexpr (BF16OUT) {
                    ((__hip_bfloat16*)Cout)[idx] = __float2bfloat16(v);
                } else {
                    ((float*)Cout)[idx] = v + residual[idx];
                }
            }
        }
    }
}

// ---------------------------------------------------------------------------
// MFMA flash attention, causal, SWAPPED QK^T (mfma(K,Q): C cols = q).
// Block = (b,h, q-tile): grid 1024. bh = bid & 63 so all q-tiles of a head
// land on one XCD (launch idx = same mod 8) -> KV shared in that XCD's L2.
// Heavy q-tiles first. 4 waves x 32 q rows. KV dbuf in LDS; V transposed.
// log2-domain softmax (Q pre-scaled by 0.125*log2e); defer-max (THR=8).
// qkv layout: [M, 3072] (q|k|v); out: [M, 1024].
// ---------------------------------------------------------------------------
__global__ __launch_bounds__(256)
void flash_attn(const __hip_bfloat16* __restrict__ qkv,
                __hip_bfloat16* __restrict__ og) {
    __shared__ __align__(16) short sK[2][KVBLK * 64];    // [kv][d] swizzled 16B slots
    __shared__ __align__(16) short sVt[2][64 * KVBLK];   // [d][kv] swizzled
    __shared__ __align__(16) short sP[4][32 * 72];       // [q][kv] per-wave, padded

    const int tid = threadIdx.x;
    const int lane = tid & 63;
    const int wv = tid >> 6;      // 0..3
    const int fr = lane & 15;
    const int g = lane >> 4;

    const int bh = blockIdx.x & 63;           // same-head blocks -> same XCD
    const int bq = 15 - (int)(blockIdx.x >> 6);  // heavy tiles first
    const int b = bh >> 4, h = bh & 15;
    const int q0 = bq * QBLK;

    const __hip_bfloat16* qp = qkv + (size_t)b * S * QKVW + h * D;
    const __hip_bfloat16* kp = qp + HD;
    const unsigned short* vp16 = (const unsigned short*)(qp + 2 * HD);
    const size_t ogBase = (size_t)b * S * HD + h * D;

    // staging indices
    const int krow = tid >> 3;    // 0..31 (+32 on it=1)
    const int kslot = tid & 7;

    // Q fragments (B-operand), scaled by 0.125 * log2(e) (log2-domain softmax)
    const float qscale = 0.125f * 1.44269504088896f;
    bf16x8 qa[2][2];
#pragma unroll
    for (int mt = 0; mt < 2; ++mt)
#pragma unroll
        for (int c = 0; c < 2; ++c) {
            bf16x8 t = *(const bf16x8*)&qp[(size_t)(q0 + wv * 32 + mt * 16 + fr) * QKVW + c * 32 + g * 8];
            bf16x8 r;
#pragma unroll
            for (int j = 0; j < 8; ++j) {
                short sb = t[j];
                __hip_bfloat16 hb = *(__hip_bfloat16*)&sb;
                float f = __bfloat162float(hb) * qscale;
                __hip_bfloat16 ob = __float2bfloat16(f);
                r[j] = *(short*)&ob;
            }
            qa[mt][c] = r;
        }

    f32x4 Oacc[2][4] = {};
    float mrun[2] = {-1e30f, -1e30f}, lrun[2] = {0.f, 0.f};

    const int kvmax = 2 * bq + 1;             // inclusive last kv tile
    const int qmaxw = q0 + wv * 32 + 31;

    // prologue: prefetch tile 0 into regs
    bf16x8 kpre[2], vpre[2];
#pragma unroll
    for (int it = 0; it < 2; ++it) {
        kpre[it] = *(const bf16x8*)&kp[(size_t)(krow + it * 32) * QKVW + kslot * 8];
#pragma unroll
        for (int j = 0; j < 8; ++j)
            vpre[it][j] = (short)vp16[(size_t)((wv + it * 4) * 8 + j) * QKVW + lane];
    }

    for (int kvt = 0; kvt <= kvmax; ++kvt) {
        const int kv0 = kvt * KVBLK;
        const int cur = kvt & 1;

        // write prefetched tile to LDS (b128 swizzled)
#pragma unroll
        for (int it = 0; it < 2; ++it) {
            const int r = krow + it * 32;
            *(bf16x8*)&sK[cur][r * 64 + ((kslot ^ (r & 7)) * 8)] = kpre[it];
            *(bf16x8*)&sVt[cur][lane * 64 + (((wv + it * 4) ^ (lane & 7)) * 8)] = vpre[it];
        }
        __syncthreads();

        // issue next tile's global loads (land during this tile's compute)
        if (kvt < kvmax) {
            const int kv0n = kv0 + KVBLK;
#pragma unroll
            for (int it = 0; it < 2; ++it) {
                kpre[it] = *(const bf16x8*)&kp[(size_t)(kv0n + krow + it * 32) * QKVW + kslot * 8];
#pragma unroll
                for (int j = 0; j < 8; ++j)
                    vpre[it][j] = (short)vp16[(size_t)(kv0n + (wv + it * 4) * 8 + j) * QKVW + lane];
            }
        }

        if (kv0 <= qmaxw) {   // wave skips fully-masked tiles
            // QK^T swapped: sf[mt][nt]: q=mt*16+fr (col), kv=nt*16+g*4+r (row)
            f32x4 sf[2][4] = {};
#pragma unroll
            for (int nt = 0; nt < 4; ++nt) {
                const int kr = nt * 16 + fr;
#pragma unroll
                for (int c = 0; c < 2; ++c) {
                    bf16x8 kb = *(const bf16x8*)&sK[cur][kr * 64 + (((c * 4 + g) ^ (kr & 7)) * 8)];
#pragma unroll
                    for (int mt = 0; mt < 2; ++mt)
                        sf[mt][nt] = __builtin_amdgcn_mfma_f32_16x16x32_bf16(kb, qa[mt][c], sf[mt][nt], 0, 0, 0);
                }
            }

#pragma unroll
            for (int mt = 0; mt < 2; ++mt) {
                const int qabs = q0 + wv * 32 + mt * 16 + fr;
                // causal mask (diagonal tiles only)
                if (kv0 + KVBLK - 1 > q0 + wv * 32 + mt * 16) {
#pragma unroll
                    for (int nt = 0; nt < 4; ++nt)
#pragma unroll
                        for (int r = 0; r < 4; ++r)
                            if (kv0 + nt * 16 + g * 4 + r > qabs) sf[mt][nt][r] = -1e30f;
                }
                // in-lane max over 16 + cross-g reduce
                float mx = -1e30f;
#pragma unroll
                for (int nt = 0; nt < 4; ++nt)
#pragma unroll
                    for (int r = 0; r < 4; ++r) mx = fmaxf(mx, sf[mt][nt][r]);
                mx = fmaxf(mx, __shfl_xor(mx, 16));
                mx = fmaxf(mx, __shfl_xor(mx, 32));

                // defer-max (T13): skip rescale when growth <= 8 (log2 domain)
                const bool nores = __all(mx <= mrun[mt] + 8.f);
                const float mnew = nores ? mrun[mt] : fmaxf(mrun[mt], mx);

                float rs = 0.f;
#pragma unroll
                for (int nt = 0; nt < 4; ++nt)
#pragma unroll
                    for (int r = 0; r < 4; ++r) {
                        float pv = exp2f(sf[mt][nt][r] - mnew);
                        sf[mt][nt][r] = pv;
                        rs += pv;
                    }
                rs += __shfl_xor(rs, 16);
                rs += __shfl_xor(rs, 32);

                if (nores) {
                    lrun[mt] += rs;
                } else {
                    const float corr = exp2f(mrun[mt] - mnew);
                    lrun[mt] = lrun[mt] * corr + rs;
                    mrun[mt] = mnew;
#pragma unroll
                    for (int r = 0; r < 4; ++r) {
                        const float corrO = __shfl(corr, g * 4 + r);
#pragma unroll
                        for (int nt = 0; nt < 4; ++nt) Oacc[mt][nt][r] *= corrO;
                    }
                }

                // pack P (4 kv-consecutive bf16) -> b64 LDS writes
#pragma unroll
                for (int nt = 0; nt < 4; ++nt) {
                    ushort4 pk;
#pragma unroll
                    for (int r = 0; r < 4; ++r) {
                        __hip_bfloat16 pb = __float2bfloat16(sf[mt][nt][r]);
                        ((unsigned short*)&pk)[r] = *(unsigned short*)&pb;
                    }
                    *(ushort4*)&sP[wv][(mt * 16 + fr) * 72 + nt * 16 + g * 4] = pk;
                }
            }

            // PV: O += P @ V (wave-private sP; b128 reads)
#pragma unroll
            for (int cp = 0; cp < 2; ++cp) {
                bf16x8 pa[2];
#pragma unroll
                for (int mt = 0; mt < 2; ++mt)
                    pa[mt] = *(const bf16x8*)&sP[wv][(mt * 16 + fr) * 72 + cp * 32 + g * 8];
#pragma unroll
                for (int nt = 0; nt < 4; ++nt) {
                    const int vrow = nt * 16 + fr;
                    bf16x8 vb = *(const bf16x8*)&sVt[cur][vrow * 64 + (((cp * 4 + g) ^ (vrow & 7)) * 8)];
#pragma unroll
                    for (int mt = 0; mt < 2; ++mt)
                        Oacc[mt][nt] = __builtin_amdgcn_mfma_f32_16x16x32_bf16(pa[mt], vb, Oacc[mt][nt], 0, 0, 0);
                }
            }
        }
    }

    // epilogue: O / l -> bf16  (q=mt*16+g*4+r, d=nt*16+fr)
#pragma unroll
    for (int mt = 0; mt < 2; ++mt) {
        float rl[4];
#pragma unroll
        for (int r = 0; r < 4; ++r) rl[r] = 1.f / __shfl(lrun[mt], g * 4 + r);
#pragma unroll
        for (int nt = 0; nt < 4; ++nt) {
            const int d = nt * 16 + fr;
#pragma unroll
            for (int r = 0; r < 4; ++r) {
                const int qrow = q0 + wv * 32 + mt * 16 + g * 4 + r;
                og[ogBase + (size_t)qrow * HD + d] = __float2bfloat16(Oacc[mt][nt][r] * rl[r]);
            }
        }
    }
}

// ---------------------------------------------------------------------------
extern "C" void kernel_launch(void* const* d_in, const int* in_sizes, int n_in,
                              void* d_out, int out_size, void* d_ws, size_t ws_size,
                              hipStream_t stream) {
    const float* x     = (const float*)d_in[0];
    const float* gamma = (const float*)d_in[1];
    const float* beta  = (const float*)d_in[2];
    const float* Wq    = (const float*)d_in[3];
    const float* bq    = (const float*)d_in[4];
    const float* Wk    = (const float*)d_in[5];
    const float* bk    = (const float*)d_in[6];
    const float* Wv    = (const float*)d_in[7];
    const float* bv    = (const float*)d_in[8];
    const float* Wo    = (const float*)d_in[9];
    const float* bo    = (const float*)d_in[10];
    float* out = (float*)d_out;

    const size_t nTok = (size_t)M_ROWS;
    __hip_bfloat16* xn    = (__hip_bfloat16*)d_ws;            // [M,E]    16 MB
    __hip_bfloat16* qkv   = xn + nTok * E;                    // [M,3072] 48 MB
    __hip_bfloat16* ao    = qkv + nTok * QKVW;                // [M,HD]   16 MB
    __hip_bfloat16* Wqkvt = ao + nTok * HD;                   // [3072,E]  6 MB
    __hip_bfloat16* Wot   = Wqkvt + (size_t)QKVW * E;         // [E,HD]    2 MB
    float* bqkv           = (float*)(Wot + (size_t)E * HD);   // [3072]

    // 0. weights -> bf16 transposed; biases packed
    dim3 tg(16, 16);
    transpose_to_bf16<<<tg, 256, 0, stream>>>(Wq, Wqkvt,                      E, HD);
    transpose_to_bf16<<<tg, 256, 0, stream>>>(Wk, Wqkvt + (size_t)HD * E,     E, HD);
    transpose_to_bf16<<<tg, 256, 0, stream>>>(Wv, Wqkvt + (size_t)2 * HD * E, E, HD);
    transpose_to_bf16<<<tg, 256, 0, stream>>>(Wo, Wot, HD, E);
    pack_bias<<<1, HD, 0, stream>>>(bq, bk, bv, bqkv);

    // 1. LayerNorm
    ln_kernel<<<M_ROWS, 256, 0, stream>>>(x, gamma, beta, xn);

    // 2. fused QKV projection [M,3072]
    dim3 gg(QKVW / 128, M_ROWS / 128);   // (24, 64)
    gemm_mfma<true><<<gg, 256, 0, stream>>>(xn, Wqkvt, bqkv, nullptr, qkv, M_ROWS, QKVW, E);

    // 3. flash attention (swapped QK^T, log2 softmax, defer-max)
    flash_attn<<<dim3(B * H * (S / QBLK)), 256, 0, stream>>>(qkv, ao);

    // 4. output projection + bias + residual
    dim3 go(E / 128, M_ROWS / 128);      // (8, 64)
    gemm_mfma<false><<<go, 256, 0, stream>>>(ao, Wot, bo, x, (void*)out, M_ROWS, E, HD);
}